// Round 12
// baseline (261.582 us; speedup 1.0000x reference)
//
#include <hip/hip_runtime.h>

// SmoothGCN: out = ((x@Wn + bn) + (segsum(x[src]*w, dst)@We + be)) @ Wm + bm
// Refactor: y = x@We; h = x@Wn + bn + be; h[dst] += w_e*y[src]; out = h@Wm + bm
// R18: R17 failed in-container twice; the one risky construct was
// launch_bounds(512,8) (VGPR cap 64 -> spill/alloc hazard) and it was
// UNNECESSARY: runtime occupancy follows actual resources (VGPR=44 measured,
// 32KB LDS, 512 thr) -> 4 blocks/CU already under the proven (512,4) bound.
// This round: identical to R17 except fuse1 back to launch_bounds(512,4).
// Retained: EPB=2048 (binC LDS 28.7KB, union 32KB), mod-2 binC||gemm1
// interleave, k0-zeroed cursor, R4-form gatherB + gemm2.

constexpr int N_NODES  = 50000;
constexpr int N_EDGES  = 1600000;
constexpr int IN_FEAT  = 256;
constexpr int HID      = 128;
constexpr int OUT_FEAT = 256;

constexpr int BIN_SZ   = 32;                                // nodes per bin
constexpr int N_BINS   = (N_NODES + BIN_SZ - 1) / BIN_SZ;   // 1563
constexpr int CAPBIN   = 1536;   // mean 1024, multinomial max ~1150, P(>1536)~0
constexpr int EPB      = 2048;   // edges per binC block
constexpr int N_CBLK   = (N_EDGES + EPB - 1) / EPB;         // 782
constexpr int GRID_M   = (N_NODES + 127) / 128;             // 391
constexpr int N_G1BLK  = GRID_M * 2;                        // 782 == N_CBLK

typedef __attribute__((ext_vector_type(8))) short bf16x8;
typedef __attribute__((ext_vector_type(8))) unsigned short u16x8;
typedef __attribute__((ext_vector_type(4))) float f32x4;

static __device__ __forceinline__ unsigned short f2bf(float f) {
    unsigned u = __builtin_bit_cast(unsigned, f);
    u += 0x7FFF + ((u >> 16) & 1);          // round-to-nearest-even
    return (unsigned short)(u >> 16);
}
static __device__ __forceinline__ float bflo(unsigned u) {
    return __builtin_bit_cast(float, u << 16);
}
static __device__ __forceinline__ float bfhi(unsigned u) {
    return __builtin_bit_cast(float, u & 0xFFFF0000u);
}

// ---------------- k0: transpose+convert weights to bf16 (+ cursor zero) ---
__global__ __launch_bounds__(256) void k0_convert(
    const float* __restrict__ Wn, const float* __restrict__ We,
    const float* __restrict__ Wm,
    unsigned short* __restrict__ Wcat_t, unsigned short* __restrict__ Wmt,
    int* __restrict__ cursor)
{
    int n = blockIdx.x;      // 0..255
    int k = threadIdx.x;     // 0..255
    float v = (n < HID) ? Wn[(size_t)k * HID + n] : We[(size_t)k * HID + (n - HID)];
    Wcat_t[(size_t)n * IN_FEAT + k] = f2bf(v);
    if (k < HID) Wmt[(size_t)n * HID + k] = f2bf(Wm[(size_t)k * OUT_FEAT + n]);
    int g = n * 256 + k;
    if (g < N_BINS) cursor[g] = 0;
}

// ---------------- fuse1: binC || gemm1, roles interleaved mod 2 -----------
union SharedU {
    struct {
        int  hist[N_BINS];
        int  gbase[N_BINS];
        int  wsum[8];
        int  stot;
        int2 sorted[EPB];            // 16 KB
    } bc;                            // ~28.7 KB
    struct {
        unsigned short As[128][64];  // 16 KB
        unsigned short Bs[128][64];  // 16 KB
    } g1;                            // 32 KB
};

__global__ __launch_bounds__(512, 4) void fuse1(
    const int* __restrict__ src, const int* __restrict__ dst,
    const float* __restrict__ w, int* __restrict__ cursor,
    int2* __restrict__ entries,
    const float* __restrict__ x, const unsigned short* __restrict__ Wcat_t,
    const float* __restrict__ bn, const float* __restrict__ be,
    float* __restrict__ h0, unsigned short* __restrict__ ybf)
{
    __shared__ SharedU sh;
    const int t = threadIdx.x;
    const int wave = t >> 6, lane = t & 63;
    const int r = blockIdx.x;                 // 0..1563

    if ((r & 1) == 0) {
        // ================= binC role (block bcid = r/2) ================
        const int e0 = (r >> 1) * EPB;

        for (int i = t; i < N_BINS; i += 512) sh.bc.hist[i] = 0;
        __syncthreads();

        int meta[4], wb[4], rk[4], bin[4];
        #pragma unroll
        for (int k = 0; k < 4; ++k) {
            int e = e0 + t + k * 512;
            bin[k] = -1;
            if (e < N_EDGES) {
                int d = dst[e];
                int b = d >> 5;
                bin[k]  = b;
                meta[k] = src[e] | ((d & 31) << 16) | (b << 21);  // src<65536 ok
                wb[k]   = __float_as_int(w[e]);
                rk[k]   = atomicAdd(&sh.bc.hist[b], 1);
            }
        }
        __syncthreads();

        // block exclusive scan of hist (4 contiguous bins per thread)
        const int b4 = t * 4;
        int c0 = 0, c1 = 0, c2 = 0, c3 = 0;
        if (b4 + 0 < N_BINS) c0 = sh.bc.hist[b4 + 0];
        if (b4 + 1 < N_BINS) c1 = sh.bc.hist[b4 + 1];
        if (b4 + 2 < N_BINS) c2 = sh.bc.hist[b4 + 2];
        if (b4 + 3 < N_BINS) c3 = sh.bc.hist[b4 + 3];
        const int s = c0 + c1 + c2 + c3;
        int pre = s;
        #pragma unroll
        for (int off = 1; off < 64; off <<= 1) {
            int o = __shfl_up(pre, off, 64);
            if (lane >= off) pre += o;
        }
        if (lane == 63) sh.bc.wsum[wave] = pre;
        __syncthreads();
        if (t == 0) {
            int rr = 0;
            #pragma unroll
            for (int q = 0; q < 8; ++q) { int v = sh.bc.wsum[q]; sh.bc.wsum[q] = rr; rr += v; }
            sh.bc.stot = rr;
        }
        __syncthreads();
        const int tb = sh.bc.wsum[wave] + pre - s;   // exclusive base for bin b4

        if (b4 + 0 < N_BINS) {
            sh.bc.hist[b4 + 0]  = tb;
            sh.bc.gbase[b4 + 0] = c0 ? atomicAdd(&cursor[b4 + 0], c0) : 0;
        }
        if (b4 + 1 < N_BINS) {
            sh.bc.hist[b4 + 1]  = tb + c0;
            sh.bc.gbase[b4 + 1] = c1 ? atomicAdd(&cursor[b4 + 1], c1) : 0;
        }
        if (b4 + 2 < N_BINS) {
            sh.bc.hist[b4 + 2]  = tb + c0 + c1;
            sh.bc.gbase[b4 + 2] = c2 ? atomicAdd(&cursor[b4 + 2], c2) : 0;
        }
        if (b4 + 3 < N_BINS) {
            sh.bc.hist[b4 + 3]  = tb + c0 + c1 + c2;
            sh.bc.gbase[b4 + 3] = c3 ? atomicAdd(&cursor[b4 + 3], c3) : 0;
        }
        __syncthreads();

        // scatter to LDS in bin-sorted order
        #pragma unroll
        for (int k = 0; k < 4; ++k)
            if (bin[k] >= 0)
                sh.bc.sorted[sh.bc.hist[bin[k]] + rk[k]] = make_int2(meta[k], wb[k]);
        __syncthreads();

        // grouped write-out: lanes cover consecutive sorted slots
        const int tot = sh.bc.stot;
        #pragma unroll
        for (int k = 0; k < 4; ++k) {
            int i = t + k * 512;
            if (i < tot) {
                int2 q = sh.bc.sorted[i];
                int b = ((unsigned)q.x) >> 21;          // bin (unsigned shift!)
                int rr = i - sh.bc.hist[b];             // rank within (block,bin)
                int g = sh.bc.gbase[b] + rr;
                if (g < CAPBIN)
                    entries[(size_t)b * CAPBIN + g] = make_int2(q.x & 0x1FFFFF, q.y);
            }
        }
    } else {
        // ============ gemm1 role (block g1id = r/2) ====================
        const int bid2 = r >> 1;                 // 0..781
        const int m0 = (bid2 >> 1) * 128;
        const int nhalf = bid2 & 1;              // 0 -> h0, 1 -> ybf
        const int n0r = nhalf * 128;

        const int wm = wave >> 2, wn = wave & 3; // 2 x 4 wave grid
        const int la = lane & 15, kq = lane >> 4;
        const int srow = t >> 3, sc8 = t & 7;    // staging: row 0..63, group 0..7

        f32x4 acc[4][2];
        const f32x4 zero = {0.f, 0.f, 0.f, 0.f};
        #pragma unroll
        for (int i = 0; i < 4; ++i)
            #pragma unroll
            for (int j = 0; j < 2; ++j) acc[i][j] = zero;

        const float4* xg = (const float4*)x;

        for (int kt = 0; kt < 4; ++kt) {
            if (kt) __syncthreads();
            // As[128][64] <- bf16(x rows m0.., cols kt*64..+63), swizzled
            #pragma unroll
            for (int i = 0; i < 2; ++i) {
                int row = srow + i * 64;
                int node = m0 + row;
                float4 v0 = make_float4(0.f, 0.f, 0.f, 0.f), v1 = v0;
                if (node < N_NODES) {
                    v0 = xg[(size_t)node * 64 + kt * 16 + sc8 * 2];
                    v1 = xg[(size_t)node * 64 + kt * 16 + sc8 * 2 + 1];
                }
                u16x8 b;
                b[0] = f2bf(v0.x); b[1] = f2bf(v0.y); b[2] = f2bf(v0.z); b[3] = f2bf(v0.w);
                b[4] = f2bf(v1.x); b[5] = f2bf(v1.y); b[6] = f2bf(v1.z); b[7] = f2bf(v1.w);
                *(u16x8*)&sh.g1.As[row][(sc8 ^ (row & 7)) * 8] = b;
            }
            // Bs[128][64] <- Wcat_t rows n0r..n0r+127, cols kt*64..+63
            #pragma unroll
            for (int i = 0; i < 2; ++i) {
                int row = srow + i * 64;
                float4 v = *(const float4*)(
                    Wcat_t + (size_t)(n0r + row) * IN_FEAT + kt * 64 + sc8 * 8);
                *(float4*)&sh.g1.Bs[row][(sc8 ^ (row & 7)) * 8] = v;
            }
            __syncthreads();

            #pragma unroll
            for (int ks = 0; ks < 2; ++ks) {
                bf16x8 a[4], b[2];
                #pragma unroll
                for (int i = 0; i < 4; ++i) {
                    int row = wm * 64 + i * 16 + la;
                    a[i] = *(const bf16x8*)&sh.g1.As[row][((ks * 4 + kq) ^ (row & 7)) * 8];
                }
                #pragma unroll
                for (int j = 0; j < 2; ++j) {
                    int row = wn * 32 + j * 16 + la;
                    b[j] = *(const bf16x8*)&sh.g1.Bs[row][((ks * 4 + kq) ^ (row & 7)) * 8];
                }
                #pragma unroll
                for (int i = 0; i < 4; ++i)
                    #pragma unroll
                    for (int j = 0; j < 2; ++j)
                        acc[i][j] = __builtin_amdgcn_mfma_f32_16x16x32_bf16(
                            a[i], b[j], acc[i][j], 0, 0, 0);
            }
        }

        float bias[2];
        if (nhalf == 0) {
            #pragma unroll
            for (int j = 0; j < 2; ++j) {
                int n = wn * 32 + j * 16 + la;
                bias[j] = bn[n] + be[n];
            }
        }
        #pragma unroll
        for (int i = 0; i < 4; ++i) {
            int mbase = m0 + wm * 64 + i * 16 + kq * 4;
            #pragma unroll
            for (int j = 0; j < 2; ++j) {
                int n = wn * 32 + j * 16 + la;
                #pragma unroll
                for (int rr = 0; rr < 4; ++rr) {
                    int m = mbase + rr;
                    if (m < N_NODES) {
                        if (nhalf == 0)
                            h0[(size_t)m * HID + n] = acc[i][j][rr] + bias[j];
                        else
                            ybf[(size_t)m * HID + n] = f2bf(acc[i][j][rr]);
                    }
                }
            }
        }
    }
}

// ---------------- gatherB: LDS node sort + register-acc gather ------------
// (R4/R9 form verbatim -- proven best.)
__global__ __launch_bounds__(512) void gatherB(
    const unsigned short* __restrict__ ybf, const float* __restrict__ h0,
    const int* __restrict__ cursor, const int2* __restrict__ entries,
    unsigned short* __restrict__ hbf)
{
    __shared__ int2 sorted[CAPBIN];   // 12 KB
    __shared__ int  cnt32[BIN_SZ];
    __shared__ int  offs32[BIN_SZ];

    const int t = threadIdx.x;
    const int bin = blockIdx.x;
    const int node0 = bin * BIN_SZ;
    const int wave = t >> 6, lane = t & 63;

    const int tot = min(cursor[bin], CAPBIN);
    if (t < BIN_SZ) cnt32[t] = 0;
    __syncthreads();

    // pass A: read my <=3 entries (coalesced, dense), rank within dst node
    int2 held[3];
    int  hrank[3], hdloc[3];
    #pragma unroll
    for (int k = 0; k < 3; ++k) {
        hdloc[k] = -1;
        int g = t + k * 512;
        if (g < tot) {
            int2 ep = entries[(size_t)bin * CAPBIN + g];
            int dloc = ep.x >> 16;                  // 5 bits (bin stripped)
            held[k]  = make_int2(ep.x & 0xFFFF, ep.y);
            hdloc[k] = dloc;
            hrank[k] = atomicAdd(&cnt32[dloc], 1);
        }
    }
    __syncthreads();

    // scan cnt32 -> offs32 (wave 0, shfl prefix over 32 lanes)
    if (wave == 0) {
        int v = (lane < BIN_SZ) ? cnt32[lane] : 0;
        int sum = v;
        #pragma unroll
        for (int off = 1; off < BIN_SZ; off <<= 1) {
            int o = __shfl_up(sum, off, 64);
            if (lane >= off) sum += o;
        }
        if (lane < BIN_SZ) offs32[lane] = sum - v;
    }
    __syncthreads();

    // pass B: scatter held entries to node-sorted order
    #pragma unroll
    for (int k = 0; k < 3; ++k)
        if (hdloc[k] >= 0)
            sorted[offs32[hdloc[k]] + hrank[k]] = held[k];
    __syncthreads();

    // per-node gather, register accumulation
    #pragma unroll
    for (int n4 = 0; n4 < 4; ++n4) {
        const int nl = wave * 4 + n4;
        const int node = node0 + nl;
        const int beg = offs32[nl];
        const int c = cnt32[nl];
        float a0 = 0.f, a1 = 0.f;
        int j = 0;
        for (; j + 4 <= c; j += 4) {
            int2 q0 = sorted[beg + j];       // ds_read_b64, broadcast
            int2 q1 = sorted[beg + j + 1];
            int2 q2 = sorted[beg + j + 2];
            int2 q3 = sorted[beg + j + 3];
            unsigned u0 = *(const unsigned*)&ybf[(size_t)q0.x * HID + 2 * lane];
            unsigned u1 = *(const unsigned*)&ybf[(size_t)q1.x * HID + 2 * lane];
            unsigned u2 = *(const unsigned*)&ybf[(size_t)q2.x * HID + 2 * lane];
            unsigned u3 = *(const unsigned*)&ybf[(size_t)q3.x * HID + 2 * lane];
            float w0 = __int_as_float(q0.y), w1 = __int_as_float(q1.y);
            float w2 = __int_as_float(q2.y), w3 = __int_as_float(q3.y);
            a0 += w0 * bflo(u0); a1 += w0 * bfhi(u0);
            a0 += w1 * bflo(u1); a1 += w1 * bfhi(u1);
            a0 += w2 * bflo(u2); a1 += w2 * bfhi(u2);
            a0 += w3 * bflo(u3); a1 += w3 * bfhi(u3);
        }
        for (; j < c; ++j) {
            int2 q = sorted[beg + j];
            unsigned u = *(const unsigned*)&ybf[(size_t)q.x * HID + 2 * lane];
            float wq = __int_as_float(q.y);
            a0 += wq * bflo(u); a1 += wq * bfhi(u);
        }
        if (node < N_NODES) {
            float2 hv = *(const float2*)&h0[(size_t)node * HID + 2 * lane];
            unsigned r = ((unsigned)f2bf(hv.y + a1) << 16)
                       | (unsigned)f2bf(hv.x + a0);
            *(unsigned*)&hbf[(size_t)node * HID + 2 * lane] = r;
        }
    }
}

// ---------------- GEMM2: out = hbf@Wm + bm ----------------
// (R4 form verbatim -- BK=64, both operands bf16, reg-staged, XOR swizzle.)
__global__ __launch_bounds__(256, 4) void gemm2(
    const unsigned short* __restrict__ hbf, const unsigned short* __restrict__ Wmt,
    const float* __restrict__ bm, float* __restrict__ out)
{
    __shared__ unsigned short As[128][64];
    __shared__ unsigned short Bs[128][64];
    const int t = threadIdx.x;
    const int m0 = blockIdx.x * 128;
    const int n0 = blockIdx.y * 128;

    const int wave = t >> 6, lane = t & 63;
    const int wm = wave & 1, wn = wave >> 1;
    const int la = lane & 15, kq = lane >> 4;
    const int srow = t >> 3, sc8 = t & 7;

    f32x4 acc[4][4];
    const f32x4 zero = {0.f, 0.f, 0.f, 0.f};
    #pragma unroll
    for (int i = 0; i < 4; ++i)
        #pragma unroll
        for (int j = 0; j < 4; ++j) acc[i][j] = zero;

    for (int kt = 0; kt < 2; ++kt) {
        if (kt) __syncthreads();
        #pragma unroll
        for (int i = 0; i < 4; ++i) {
            int row = srow + i * 32;
            int node = m0 + row;
            if (node >= N_NODES) node = N_NODES - 1;   // dup row; dropped at store
            float4 va = *(const float4*)(hbf + (size_t)node * HID + kt * 64 + sc8 * 8);
            float4 vb = *(const float4*)(Wmt + (size_t)(n0 + row) * HID + kt * 64 + sc8 * 8);
            *(float4*)&As[row][(sc8 ^ (row & 7)) * 8] = va;
            *(float4*)&Bs[row][(sc8 ^ (row & 7)) * 8] = vb;
        }
        __syncthreads();

        #pragma unroll
        for (int ks = 0; ks < 2; ++ks) {
            bf16x8 a[4], b[4];
            #pragma unroll
            for (int i = 0; i < 4; ++i) {
                int row = wm * 64 + i * 16 + la;
                a[i] = *(const bf16x8*)&As[row][((ks * 4 + kq) ^ (row & 7)) * 8];
            }
            #pragma unroll
            for (int j = 0; j < 4; ++j) {
                int row = wn * 64 + j * 16 + la;
                b[j] = *(const bf16x8*)&Bs[row][((ks * 4 + kq) ^ (row & 7)) * 8];
            }
            #pragma unroll
            for (int i = 0; i < 4; ++i)
                #pragma unroll
                for (int j = 0; j < 4; ++j)
                    acc[i][j] = __builtin_amdgcn_mfma_f32_16x16x32_bf16(
                        a[i], b[j], acc[i][j], 0, 0, 0);
        }
    }

    #pragma unroll
    for (int i = 0; i < 4; ++i) {
        int mbase = m0 + wm * 64 + i * 16 + kq * 4;
        #pragma unroll
        for (int j = 0; j < 4; ++j) {
            int n = n0 + wn * 64 + j * 16 + la;
            float b = bm[n];
            #pragma unroll
            for (int r = 0; r < 4; ++r) {
                int m = mbase + r;
                if (m < N_NODES)
                    out[(size_t)m * OUT_FEAT + n] = acc[i][j][r] + b;
            }
        }
    }
}

extern "C" void kernel_launch(void* const* d_in, const int* in_sizes, int n_in,
                              void* d_out, int out_size, void* d_ws, size_t ws_size,
                              hipStream_t stream) {
    const float* x   = (const float*)d_in[0];
    const float* w   = (const float*)d_in[1];
    const int*   src = (const int*)d_in[2];
    const int*   dst = (const int*)d_in[3];
    const float* Wn  = (const float*)d_in[4];
    const float* bn  = (const float*)d_in[5];
    const float* We  = (const float*)d_in[6];
    const float* be  = (const float*)d_in[7];
    const float* Wm  = (const float*)d_in[8];
    const float* bm  = (const float*)d_in[9];
    float* out = (float*)d_out;

    char* p = (char*)d_ws;
    float*          h0      = (float*)p;          p += (size_t)N_NODES * HID * 4;        // 25.6 MB
    unsigned short* ybf     = (unsigned short*)p; p += (size_t)N_NODES * HID * 2;        // 12.8 MB
    unsigned short* hbf     = (unsigned short*)p; p += (size_t)N_NODES * HID * 2;        // 12.8 MB
    int2*           entries = (int2*)p;           p += (size_t)N_BINS * CAPBIN * 8;      // 19.2 MB
    unsigned short* Wcat_t  = (unsigned short*)p; p += (size_t)256 * IN_FEAT * 2;        // 128 KB
    unsigned short* Wmt     = (unsigned short*)p; p += (size_t)OUT_FEAT * HID * 2;       // 64 KB
    int*            cursor  = (int*)p;            p += (size_t)N_BINS * 4;               // 6.3 KB

    dim3 blk(256);

    k0_convert<<<256, blk, 0, stream>>>(Wn, We, Wm, Wcat_t, Wmt, cursor);
    fuse1<<<N_CBLK + N_G1BLK, dim3(512), 0, stream>>>(
        src, dst, w, cursor, entries, x, Wcat_t, bn, be, h0, ybf);
    gatherB<<<N_BINS, dim3(512), 0, stream>>>(ybf, h0, cursor, entries, hbf);
    gemm2<<<dim3(GRID_M, 2), blk, 0, stream>>>(hbf, Wmt, bm, out);
}

// Round 13
// 237.661 us; speedup vs baseline: 1.1007x; 1.1007x over previous
//
#include <hip/hip_runtime.h>

// SmoothGCN: out = ((x@Wn + bn) + (segsum(x[src]*w, dst)@We + be)) @ Wm + bm
// Refactor: y = x@We; h = x@Wn + bn + be; h[dst] += w_e*y[src]; out = h@Wm + bm
// R19: R17/R18's EPB=2048+mod-2 REGRESSED fuse1 65->89us: binC fixed costs
// (1563-bin hist zero+scan, ~1141 reserve-atomics/block) scale per block,
// and write-out segments halved (WRITE 71->79MB). Occupancy counter stayed
// 32% despite 32KB LDS -> it tracks achieved waves (dependency-stalled),
// not capacity; the whole occupancy thesis is dead. Revert to R9 (245.9us
// best: EPB=4096, mod-3 interleave) + two zero-risk trims: k0 zeroes
// cursor (memset dispatch dropped) and gemm2 grid dim3(2,GRID_M) so both
// n-tiles of one m-panel dispatch adjacently (hbf read L2-hot 2nd time).

constexpr int N_NODES  = 50000;
constexpr int N_EDGES  = 1600000;
constexpr int IN_FEAT  = 256;
constexpr int HID      = 128;
constexpr int OUT_FEAT = 256;

constexpr int BIN_SZ   = 32;                                // nodes per bin
constexpr int N_BINS   = (N_NODES + BIN_SZ - 1) / BIN_SZ;   // 1563
constexpr int CAPBIN   = 1536;   // mean 1024, multinomial max ~1150, P(>1536)~0
constexpr int EPB      = 4096;   // edges per binC block
constexpr int N_CBLK   = (N_EDGES + EPB - 1) / EPB;         // 391
constexpr int GRID_M   = (N_NODES + 127) / 128;             // 391
constexpr int N_G1BLK  = GRID_M * 2;                        // 782

typedef __attribute__((ext_vector_type(8))) short bf16x8;
typedef __attribute__((ext_vector_type(8))) unsigned short u16x8;
typedef __attribute__((ext_vector_type(4))) float f32x4;

static __device__ __forceinline__ unsigned short f2bf(float f) {
    unsigned u = __builtin_bit_cast(unsigned, f);
    u += 0x7FFF + ((u >> 16) & 1);          // round-to-nearest-even
    return (unsigned short)(u >> 16);
}
static __device__ __forceinline__ float bflo(unsigned u) {
    return __builtin_bit_cast(float, u << 16);
}
static __device__ __forceinline__ float bfhi(unsigned u) {
    return __builtin_bit_cast(float, u & 0xFFFF0000u);
}

// ---------------- k0: transpose+convert weights to bf16 (+ cursor zero) ---
__global__ __launch_bounds__(256) void k0_convert(
    const float* __restrict__ Wn, const float* __restrict__ We,
    const float* __restrict__ Wm,
    unsigned short* __restrict__ Wcat_t, unsigned short* __restrict__ Wmt,
    int* __restrict__ cursor)
{
    int n = blockIdx.x;      // 0..255
    int k = threadIdx.x;     // 0..255
    float v = (n < HID) ? Wn[(size_t)k * HID + n] : We[(size_t)k * HID + (n - HID)];
    Wcat_t[(size_t)n * IN_FEAT + k] = f2bf(v);
    if (k < HID) Wmt[(size_t)n * HID + k] = f2bf(Wm[(size_t)k * OUT_FEAT + n]);
    int g = n * 256 + k;
    if (g < N_BINS) cursor[g] = 0;
}

// ---------------- fuse1: binC || gemm1, roles interleaved mod 3 -----------
// (R9 form verbatim -- part of the 245.9us best.)
union SharedU {
    struct {
        int  hist[N_BINS];
        int  gbase[N_BINS];
        int  wsum[8];
        int  stot;
        int2 sorted[EPB];            // 32 KB
    } bc;                            // ~44.3 KB
    struct {
        unsigned short As[128][64];  // 16 KB
        unsigned short Bs[128][64];  // 16 KB
    } g1;
};

__global__ __launch_bounds__(512, 4) void fuse1(
    const int* __restrict__ src, const int* __restrict__ dst,
    const float* __restrict__ w, int* __restrict__ cursor,
    int2* __restrict__ entries,
    const float* __restrict__ x, const unsigned short* __restrict__ Wcat_t,
    const float* __restrict__ bn, const float* __restrict__ be,
    float* __restrict__ h0, unsigned short* __restrict__ ybf)
{
    __shared__ SharedU sh;
    const int t = threadIdx.x;
    const int wave = t >> 6, lane = t & 63;
    const int r = blockIdx.x;                 // 0..1172 (= 3*391 - 1)

    if (r % 3 == 0) {
        // ================= binC role (block bcid = r/3) ================
        const int e0 = (r / 3) * EPB;

        for (int i = t; i < N_BINS; i += 512) sh.bc.hist[i] = 0;
        __syncthreads();

        int meta[8], wb[8], rk[8], bin[8];
        #pragma unroll
        for (int k = 0; k < 8; ++k) {
            int e = e0 + t + k * 512;
            bin[k] = -1;
            if (e < N_EDGES) {
                int d = dst[e];
                int b = d >> 5;
                bin[k]  = b;
                meta[k] = src[e] | ((d & 31) << 16) | (b << 21);  // src<65536 ok
                wb[k]   = __float_as_int(w[e]);
                rk[k]   = atomicAdd(&sh.bc.hist[b], 1);
            }
        }
        __syncthreads();

        // block exclusive scan of hist (4 contiguous bins per thread)
        const int b4 = t * 4;
        int c0 = 0, c1 = 0, c2 = 0, c3 = 0;
        if (b4 + 0 < N_BINS) c0 = sh.bc.hist[b4 + 0];
        if (b4 + 1 < N_BINS) c1 = sh.bc.hist[b4 + 1];
        if (b4 + 2 < N_BINS) c2 = sh.bc.hist[b4 + 2];
        if (b4 + 3 < N_BINS) c3 = sh.bc.hist[b4 + 3];
        const int s = c0 + c1 + c2 + c3;
        int pre = s;
        #pragma unroll
        for (int off = 1; off < 64; off <<= 1) {
            int o = __shfl_up(pre, off, 64);
            if (lane >= off) pre += o;
        }
        if (lane == 63) sh.bc.wsum[wave] = pre;
        __syncthreads();
        if (t == 0) {
            int rr = 0;
            #pragma unroll
            for (int q = 0; q < 8; ++q) { int v = sh.bc.wsum[q]; sh.bc.wsum[q] = rr; rr += v; }
            sh.bc.stot = rr;
        }
        __syncthreads();
        const int tb = sh.bc.wsum[wave] + pre - s;   // exclusive base for bin b4

        if (b4 + 0 < N_BINS) {
            sh.bc.hist[b4 + 0]  = tb;
            sh.bc.gbase[b4 + 0] = c0 ? atomicAdd(&cursor[b4 + 0], c0) : 0;
        }
        if (b4 + 1 < N_BINS) {
            sh.bc.hist[b4 + 1]  = tb + c0;
            sh.bc.gbase[b4 + 1] = c1 ? atomicAdd(&cursor[b4 + 1], c1) : 0;
        }
        if (b4 + 2 < N_BINS) {
            sh.bc.hist[b4 + 2]  = tb + c0 + c1;
            sh.bc.gbase[b4 + 2] = c2 ? atomicAdd(&cursor[b4 + 2], c2) : 0;
        }
        if (b4 + 3 < N_BINS) {
            sh.bc.hist[b4 + 3]  = tb + c0 + c1 + c2;
            sh.bc.gbase[b4 + 3] = c3 ? atomicAdd(&cursor[b4 + 3], c3) : 0;
        }
        __syncthreads();

        // scatter to LDS in bin-sorted order
        #pragma unroll
        for (int k = 0; k < 8; ++k)
            if (bin[k] >= 0)
                sh.bc.sorted[sh.bc.hist[bin[k]] + rk[k]] = make_int2(meta[k], wb[k]);
        __syncthreads();

        // grouped write-out: lanes cover consecutive sorted slots
        const int tot = sh.bc.stot;
        #pragma unroll
        for (int k = 0; k < 8; ++k) {
            int i = t + k * 512;
            if (i < tot) {
                int2 q = sh.bc.sorted[i];
                int b = ((unsigned)q.x) >> 21;          // bin (unsigned shift!)
                int rr = i - sh.bc.hist[b];             // rank within (block,bin)
                int g = sh.bc.gbase[b] + rr;
                if (g < CAPBIN)
                    entries[(size_t)b * CAPBIN + g] = make_int2(q.x & 0x1FFFFF, q.y);
            }
        }
    } else {
        // ============ gemm1 role (block g1id = r - r/3 - 1) ============
        const int bid2 = r - r / 3 - 1;          // 0..781
        const int m0 = (bid2 >> 1) * 128;
        const int nhalf = bid2 & 1;              // 0 -> h0, 1 -> ybf
        const int n0r = nhalf * 128;

        const int wm = wave >> 2, wn = wave & 3; // 2 x 4 wave grid
        const int la = lane & 15, kq = lane >> 4;
        const int srow = t >> 3, sc8 = t & 7;    // staging: row 0..63, group 0..7

        f32x4 acc[4][2];
        const f32x4 zero = {0.f, 0.f, 0.f, 0.f};
        #pragma unroll
        for (int i = 0; i < 4; ++i)
            #pragma unroll
            for (int j = 0; j < 2; ++j) acc[i][j] = zero;

        const float4* xg = (const float4*)x;

        for (int kt = 0; kt < 4; ++kt) {
            if (kt) __syncthreads();
            // As[128][64] <- bf16(x rows m0.., cols kt*64..+63), swizzled
            #pragma unroll
            for (int i = 0; i < 2; ++i) {
                int row = srow + i * 64;
                int node = m0 + row;
                float4 v0 = make_float4(0.f, 0.f, 0.f, 0.f), v1 = v0;
                if (node < N_NODES) {
                    v0 = xg[(size_t)node * 64 + kt * 16 + sc8 * 2];
                    v1 = xg[(size_t)node * 64 + kt * 16 + sc8 * 2 + 1];
                }
                u16x8 b;
                b[0] = f2bf(v0.x); b[1] = f2bf(v0.y); b[2] = f2bf(v0.z); b[3] = f2bf(v0.w);
                b[4] = f2bf(v1.x); b[5] = f2bf(v1.y); b[6] = f2bf(v1.z); b[7] = f2bf(v1.w);
                *(u16x8*)&sh.g1.As[row][(sc8 ^ (row & 7)) * 8] = b;
            }
            // Bs[128][64] <- Wcat_t rows n0r..n0r+127, cols kt*64..+63
            #pragma unroll
            for (int i = 0; i < 2; ++i) {
                int row = srow + i * 64;
                float4 v = *(const float4*)(
                    Wcat_t + (size_t)(n0r + row) * IN_FEAT + kt * 64 + sc8 * 8);
                *(float4*)&sh.g1.Bs[row][(sc8 ^ (row & 7)) * 8] = v;
            }
            __syncthreads();

            #pragma unroll
            for (int ks = 0; ks < 2; ++ks) {
                bf16x8 a[4], b[2];
                #pragma unroll
                for (int i = 0; i < 4; ++i) {
                    int row = wm * 64 + i * 16 + la;
                    a[i] = *(const bf16x8*)&sh.g1.As[row][((ks * 4 + kq) ^ (row & 7)) * 8];
                }
                #pragma unroll
                for (int j = 0; j < 2; ++j) {
                    int row = wn * 32 + j * 16 + la;
                    b[j] = *(const bf16x8*)&sh.g1.Bs[row][((ks * 4 + kq) ^ (row & 7)) * 8];
                }
                #pragma unroll
                for (int i = 0; i < 4; ++i)
                    #pragma unroll
                    for (int j = 0; j < 2; ++j)
                        acc[i][j] = __builtin_amdgcn_mfma_f32_16x16x32_bf16(
                            a[i], b[j], acc[i][j], 0, 0, 0);
            }
        }

        float bias[2];
        if (nhalf == 0) {
            #pragma unroll
            for (int j = 0; j < 2; ++j) {
                int n = wn * 32 + j * 16 + la;
                bias[j] = bn[n] + be[n];
            }
        }
        #pragma unroll
        for (int i = 0; i < 4; ++i) {
            int mbase = m0 + wm * 64 + i * 16 + kq * 4;
            #pragma unroll
            for (int j = 0; j < 2; ++j) {
                int n = wn * 32 + j * 16 + la;
                #pragma unroll
                for (int rr = 0; rr < 4; ++rr) {
                    int m = mbase + rr;
                    if (m < N_NODES) {
                        if (nhalf == 0)
                            h0[(size_t)m * HID + n] = acc[i][j][rr] + bias[j];
                        else
                            ybf[(size_t)m * HID + n] = f2bf(acc[i][j][rr]);
                    }
                }
            }
        }
    }
}

// ---------------- gatherB: LDS node sort + register-acc gather ------------
// (R4/R9 form verbatim -- proven best.)
__global__ __launch_bounds__(512) void gatherB(
    const unsigned short* __restrict__ ybf, const float* __restrict__ h0,
    const int* __restrict__ cursor, const int2* __restrict__ entries,
    unsigned short* __restrict__ hbf)
{
    __shared__ int2 sorted[CAPBIN];   // 12 KB
    __shared__ int  cnt32[BIN_SZ];
    __shared__ int  offs32[BIN_SZ];

    const int t = threadIdx.x;
    const int bin = blockIdx.x;
    const int node0 = bin * BIN_SZ;
    const int wave = t >> 6, lane = t & 63;

    const int tot = min(cursor[bin], CAPBIN);
    if (t < BIN_SZ) cnt32[t] = 0;
    __syncthreads();

    // pass A: read my <=3 entries (coalesced, dense), rank within dst node
    int2 held[3];
    int  hrank[3], hdloc[3];
    #pragma unroll
    for (int k = 0; k < 3; ++k) {
        hdloc[k] = -1;
        int g = t + k * 512;
        if (g < tot) {
            int2 ep = entries[(size_t)bin * CAPBIN + g];
            int dloc = ep.x >> 16;                  // 5 bits (bin stripped)
            held[k]  = make_int2(ep.x & 0xFFFF, ep.y);
            hdloc[k] = dloc;
            hrank[k] = atomicAdd(&cnt32[dloc], 1);
        }
    }
    __syncthreads();

    // scan cnt32 -> offs32 (wave 0, shfl prefix over 32 lanes)
    if (wave == 0) {
        int v = (lane < BIN_SZ) ? cnt32[lane] : 0;
        int sum = v;
        #pragma unroll
        for (int off = 1; off < BIN_SZ; off <<= 1) {
            int o = __shfl_up(sum, off, 64);
            if (lane >= off) sum += o;
        }
        if (lane < BIN_SZ) offs32[lane] = sum - v;
    }
    __syncthreads();

    // pass B: scatter held entries to node-sorted order
    #pragma unroll
    for (int k = 0; k < 3; ++k)
        if (hdloc[k] >= 0)
            sorted[offs32[hdloc[k]] + hrank[k]] = held[k];
    __syncthreads();

    // per-node gather, register accumulation
    #pragma unroll
    for (int n4 = 0; n4 < 4; ++n4) {
        const int nl = wave * 4 + n4;
        const int node = node0 + nl;
        const int beg = offs32[nl];
        const int c = cnt32[nl];
        float a0 = 0.f, a1 = 0.f;
        int j = 0;
        for (; j + 4 <= c; j += 4) {
            int2 q0 = sorted[beg + j];       // ds_read_b64, broadcast
            int2 q1 = sorted[beg + j + 1];
            int2 q2 = sorted[beg + j + 2];
            int2 q3 = sorted[beg + j + 3];
            unsigned u0 = *(const unsigned*)&ybf[(size_t)q0.x * HID + 2 * lane];
            unsigned u1 = *(const unsigned*)&ybf[(size_t)q1.x * HID + 2 * lane];
            unsigned u2 = *(const unsigned*)&ybf[(size_t)q2.x * HID + 2 * lane];
            unsigned u3 = *(const unsigned*)&ybf[(size_t)q3.x * HID + 2 * lane];
            float w0 = __int_as_float(q0.y), w1 = __int_as_float(q1.y);
            float w2 = __int_as_float(q2.y), w3 = __int_as_float(q3.y);
            a0 += w0 * bflo(u0); a1 += w0 * bfhi(u0);
            a0 += w1 * bflo(u1); a1 += w1 * bfhi(u1);
            a0 += w2 * bflo(u2); a1 += w2 * bfhi(u2);
            a0 += w3 * bflo(u3); a1 += w3 * bfhi(u3);
        }
        for (; j < c; ++j) {
            int2 q = sorted[beg + j];
            unsigned u = *(const unsigned*)&ybf[(size_t)q.x * HID + 2 * lane];
            float wq = __int_as_float(q.y);
            a0 += wq * bflo(u); a1 += wq * bfhi(u);
        }
        if (node < N_NODES) {
            float2 hv = *(const float2*)&h0[(size_t)node * HID + 2 * lane];
            unsigned r = ((unsigned)f2bf(hv.y + a1) << 16)
                       | (unsigned)f2bf(hv.x + a0);
            *(unsigned*)&hbf[(size_t)node * HID + 2 * lane] = r;
        }
    }
}

// ---------------- GEMM2: out = hbf@Wm + bm ----------------
// (R4 form; grid swapped to dim3(2, GRID_M) so the two n-tiles of one
//  m-panel dispatch adjacently -> hbf panel L2-hot on the second read.)
__global__ __launch_bounds__(256, 4) void gemm2(
    const unsigned short* __restrict__ hbf, const unsigned short* __restrict__ Wmt,
    const float* __restrict__ bm, float* __restrict__ out)
{
    __shared__ unsigned short As[128][64];
    __shared__ unsigned short Bs[128][64];
    const int t = threadIdx.x;
    const int m0 = blockIdx.y * 128;
    const int n0 = blockIdx.x * 128;

    const int wave = t >> 6, lane = t & 63;
    const int wm = wave & 1, wn = wave >> 1;
    const int la = lane & 15, kq = lane >> 4;
    const int srow = t >> 3, sc8 = t & 7;

    f32x4 acc[4][4];
    const f32x4 zero = {0.f, 0.f, 0.f, 0.f};
    #pragma unroll
    for (int i = 0; i < 4; ++i)
        #pragma unroll
        for (int j = 0; j < 4; ++j) acc[i][j] = zero;

    for (int kt = 0; kt < 2; ++kt) {
        if (kt) __syncthreads();
        #pragma unroll
        for (int i = 0; i < 4; ++i) {
            int row = srow + i * 32;
            int node = m0 + row;
            if (node >= N_NODES) node = N_NODES - 1;   // dup row; dropped at store
            float4 va = *(const float4*)(hbf + (size_t)node * HID + kt * 64 + sc8 * 8);
            float4 vb = *(const float4*)(Wmt + (size_t)(n0 + row) * HID + kt * 64 + sc8 * 8);
            *(float4*)&As[row][(sc8 ^ (row & 7)) * 8] = va;
            *(float4*)&Bs[row][(sc8 ^ (row & 7)) * 8] = vb;
        }
        __syncthreads();

        #pragma unroll
        for (int ks = 0; ks < 2; ++ks) {
            bf16x8 a[4], b[4];
            #pragma unroll
            for (int i = 0; i < 4; ++i) {
                int row = wm * 64 + i * 16 + la;
                a[i] = *(const bf16x8*)&As[row][((ks * 4 + kq) ^ (row & 7)) * 8];
            }
            #pragma unroll
            for (int j = 0; j < 4; ++j) {
                int row = wn * 64 + j * 16 + la;
                b[j] = *(const bf16x8*)&Bs[row][((ks * 4 + kq) ^ (row & 7)) * 8];
            }
            #pragma unroll
            for (int i = 0; i < 4; ++i)
                #pragma unroll
                for (int j = 0; j < 4; ++j)
                    acc[i][j] = __builtin_amdgcn_mfma_f32_16x16x32_bf16(
                        a[i], b[j], acc[i][j], 0, 0, 0);
        }
    }

    #pragma unroll
    for (int i = 0; i < 4; ++i) {
        int mbase = m0 + wm * 64 + i * 16 + kq * 4;
        #pragma unroll
        for (int j = 0; j < 4; ++j) {
            int n = n0 + wn * 64 + j * 16 + la;
            float b = bm[n];
            #pragma unroll
            for (int r = 0; r < 4; ++r) {
                int m = mbase + r;
                if (m < N_NODES)
                    out[(size_t)m * OUT_FEAT + n] = acc[i][j][r] + b;
            }
        }
    }
}

extern "C" void kernel_launch(void* const* d_in, const int* in_sizes, int n_in,
                              void* d_out, int out_size, void* d_ws, size_t ws_size,
                              hipStream_t stream) {
    const float* x   = (const float*)d_in[0];
    const float* w   = (const float*)d_in[1];
    const int*   src = (const int*)d_in[2];
    const int*   dst = (const int*)d_in[3];
    const float* Wn  = (const float*)d_in[4];
    const float* bn  = (const float*)d_in[5];
    const float* We  = (const float*)d_in[6];
    const float* be  = (const float*)d_in[7];
    const float* Wm  = (const float*)d_in[8];
    const float* bm  = (const float*)d_in[9];
    float* out = (float*)d_out;

    char* p = (char*)d_ws;
    float*          h0      = (float*)p;          p += (size_t)N_NODES * HID * 4;        // 25.6 MB
    unsigned short* ybf     = (unsigned short*)p; p += (size_t)N_NODES * HID * 2;        // 12.8 MB
    unsigned short* hbf     = (unsigned short*)p; p += (size_t)N_NODES * HID * 2;        // 12.8 MB
    int2*           entries = (int2*)p;           p += (size_t)N_BINS * CAPBIN * 8;      // 19.2 MB
    unsigned short* Wcat_t  = (unsigned short*)p; p += (size_t)256 * IN_FEAT * 2;        // 128 KB
    unsigned short* Wmt     = (unsigned short*)p; p += (size_t)OUT_FEAT * HID * 2;       // 64 KB
    int*            cursor  = (int*)p;            p += (size_t)N_BINS * 4;               // 6.3 KB

    dim3 blk(256);

    k0_convert<<<256, blk, 0, stream>>>(Wn, We, Wm, Wcat_t, Wmt, cursor);
    fuse1<<<N_CBLK + N_G1BLK, dim3(512), 0, stream>>>(
        src, dst, w, cursor, entries, x, Wcat_t, bn, be, h0, ybf);
    gatherB<<<N_BINS, dim3(512), 0, stream>>>(ybf, h0, cursor, entries, hbf);
    gemm2<<<dim3(2, GRID_M), blk, 0, stream>>>(hbf, Wmt, bm, out);
}